// Round 12
// baseline (210.063 us; speedup 1.0000x reference)
//
#include <hip/hip_runtime.h>

// Reference collapses: softmax over a size-1 key axis == 1.0, so
// out[bn,t,:] = padded[bn,t,:] + (masked_mean_t(padded[bn]) @ Wv + bv).
// q/k/rope/positions/sum_token are dead code.
//
// R16: persistent-pair serial kernel, 1 block/CU.  Model from 11 rounds:
// all fused variants sit at 2.4-2.6 TB/s regardless of bytes moved ->
// the cost is HBM fair-share + ~20us/CU of serial non-memory phases,
// and R8's 2 lockstep co-resident blocks contend phase-aligned (no
// complementary overlap).  This structure removes co-residency entirely:
// 256 blocks x 768 thr, block owns bnA=bid, bnB=bid+256 SERIALLY.
//  - B's first 9 row-rounds (108 KB) are DMA'd to LDS (global_load_lds,
//    un-sinkable) during A's phase-1 load burst: B's load phase shrinks
//    to 7 reg rounds, staged rows never touch global again (colsumB and
//    storeB read LDS).
//  - FETCH-54 property preserved: chip does all A-tiles then all
//    B-tiles; ~76 MB in flight max -> L3 holds re-reads.
//  - plain __syncthreads everywhere (DMAs drain inside the phase-1
//    burst; nothing stalls idle).  nt stores for out.
// Prediction: LDS ~124 KB, FETCH 50-65 MB, kernel 55-63us.
// Pre-committed: if >=69us, the ~70us plateau is structural -> ceiling.

#define DM 384
#define TT 128
#define C4 96          // DM / 4
#define NBLK 256       // 512 bn / 2 per block (serial)
#define NR  8          // row-groups (768 = 8 * 96)
#define RPT 16         // rows per thread per bn
#define NSTG 9         // B rounds staged via DMA (108 KB)
#define NREG 7         // B rounds via registers

typedef float f32x4 __attribute__((ext_vector_type(4)));

__device__ __forceinline__ void nt_store4(float4* p, const float4 v) {
    __builtin_nontemporal_store(*(const f32x4*)&v, (f32x4*)p);
}

// async global->LDS DMA, 16B per lane; lds address must be wave-uniform.
__device__ __forceinline__ void async_copy16(const void* g, void* lds) {
    __builtin_amdgcn_global_load_lds(
        (const __attribute__((address_space(1))) void*)g,
        (__attribute__((address_space(3))) void*)lds, 16, 0, 0);
}

__global__ __launch_bounds__(768, 1) void fused_persist(
    const float* __restrict__ padded,
    const int*   __restrict__ masks,
    const float* __restrict__ Wv,
    const float* __restrict__ bv,
    float*       __restrict__ out)
{
    const int bnA = blockIdx.x;
    const int bnB = blockIdx.x + NBLK;
    const int t   = threadIdx.x;
    const int c   = t % C4;              // float4 column 0..95
    const int r   = t / C4;              // row-group 0..7

    __shared__ float4 stageB[NSTG * 768];   // 108 KB, linear (DMA layout)
    __shared__ float  w_sh[2][TT];
    __shared__ float4 part_sh[NR][C4];      // 12 KB
    __shared__ float  summ[DM];

    const float4* __restrict__ pA = (const float4*)padded + (size_t)bnA * TT * C4;
    const float4* __restrict__ pB = (const float4*)padded + (size_t)bnB * TT * C4;

    if (t < TT)           w_sh[0][t]      = (float)masks[bnA * TT + t];
    else if (t < 2 * TT)  w_sh[1][t - TT] = (float)masks[bnB * TT + (t - TT)];
    __syncthreads();                     // B0: masks only (cheap drain)

    // ==== phase 1: A tile loads + B stage DMAs (one saturated burst) ====
    // flat idx i*768 + t  <->  row 8i + r, col c
    float4 x[RPT];
    #pragma unroll
    for (int i = 0; i < RPT; ++i) x[i] = pA[i * 768 + t];

    const int wbase = t & ~63;           // wave-uniform LDS base
    #pragma unroll
    for (int i = 0; i < NSTG; ++i)
        async_copy16(&pB[i * 768 + t], &stageB[i * 768 + wbase]);

    // ---- colsumA (4 accumulators; x[i] is row 8i + r) ----
    {
        float4 a0 = make_float4(0.f,0.f,0.f,0.f), a1 = a0, a2 = a0, a3 = a0;
        #pragma unroll
        for (int i = 0; i < 4; ++i) {
            const float w0 = w_sh[0][8 * (4*i    ) + r];
            const float w1 = w_sh[0][8 * (4*i + 1) + r];
            const float w2 = w_sh[0][8 * (4*i + 2) + r];
            const float w3 = w_sh[0][8 * (4*i + 3) + r];
            const float4 x0 = x[4*i], x1 = x[4*i+1], x2 = x[4*i+2], x3 = x[4*i+3];
            a0.x += x0.x*w0; a0.y += x0.y*w0; a0.z += x0.z*w0; a0.w += x0.w*w0;
            a1.x += x1.x*w1; a1.y += x1.y*w1; a1.z += x1.z*w1; a1.w += x1.w*w1;
            a2.x += x2.x*w2; a2.y += x2.y*w2; a2.z += x2.z*w2; a2.w += x2.w*w2;
            a3.x += x3.x*w3; a3.y += x3.y*w3; a3.z += x3.z*w3; a3.w += x3.w*w3;
        }
        a0.x += a1.x + a2.x + a3.x; a0.y += a1.y + a2.y + a3.y;
        a0.z += a1.z + a2.z + a3.z; a0.w += a1.w + a2.w + a3.w;
        part_sh[r][c] = a0;
    }
    __syncthreads();                     // B1: drains A loads + B DMAs

    // ---- summaryA (96 threads) ----
    if (t < C4) {
        float d0 = 0.f, d1 = 0.f, d2 = 0.f, d3 = 0.f;
        #pragma unroll
        for (int i = 0; i < 32; ++i) {
            d0 += w_sh[0][i];      d1 += w_sh[0][32 + i];
            d2 += w_sh[0][64 + i]; d3 += w_sh[0][96 + i];
        }
        const float inv = 1.0f / fmaxf((d0 + d1) + (d2 + d3), 1e-6f);
        float4 s = part_sh[0][t];
        #pragma unroll
        for (int g = 1; g < NR; ++g) {
            const float4 p = part_sh[g][t];
            s.x += p.x; s.y += p.y; s.z += p.z; s.w += p.w;
        }
        s.x *= inv; s.y *= inv; s.z *= inv; s.w *= inv;
        ((float4*)summ)[t] = s;
    }
    __syncthreads();                     // B2

    // ---- matvecA: row-group r covers Wv rows [r*48, r*48+48) ----
    {
        float4 a = make_float4(0.f, 0.f, 0.f, 0.f);
        const float4* __restrict__ wv4 = (const float4*)Wv;
        const int e0 = r * (DM / NR);
        #pragma unroll 8
        for (int i = 0; i < DM / NR; ++i) {
            const int   e = e0 + i;
            const float s = summ[e];
            const float4 w = wv4[(size_t)e * C4 + c];
            a.x += s*w.x; a.y += s*w.y; a.z += s*w.z; a.w += s*w.w;
        }
        part_sh[r][c] = a;
    }
    __syncthreads();                     // B3

    // ---- v-finalizeA + storeA (re-read pA right after matvec: L3-hot) ----
    {
        float4 v = ((const float4*)bv)[c];
        #pragma unroll
        for (int g = 0; g < NR; ++g) {
            const float4 q = part_sh[g][c];
            v.x += q.x; v.y += q.y; v.z += q.z; v.w += q.w;
        }
        float4* __restrict__ oA = (float4*)out + (size_t)bnA * TT * C4;
        #pragma unroll
        for (int i = 0; i < RPT; ++i) {
            float4 y = pA[i * 768 + t];
            y.x += v.x; y.y += v.y; y.z += v.z; y.w += v.w;
            nt_store4(&oA[i * 768 + t], y);
        }
    }
    __syncthreads();                     // B4: part_sh WAR before colsumB

    // ==== B: colsum from LDS stage (9 rounds) + reg loads (7 rounds) ====
    {
        float4 a0 = make_float4(0.f,0.f,0.f,0.f);
        float4 a1 = make_float4(0.f,0.f,0.f,0.f);
        #pragma unroll
        for (int i = 0; i < NSTG; ++i) {          // staged rows 8i + r
            const float  w  = w_sh[1][8 * i + r];
            const float4 xv = stageB[i * 768 + t];   // ds_read_b128
            a0.x += xv.x*w; a0.y += xv.y*w; a0.z += xv.z*w; a0.w += xv.w*w;
        }
        #pragma unroll
        for (int i = 0; i < NREG; ++i) {          // rows 8(9+i) + r
            const float  w  = w_sh[1][8 * (NSTG + i) + r];
            const float4 xv = pB[(NSTG + i) * 768 + t];
            a1.x += xv.x*w; a1.y += xv.y*w; a1.z += xv.z*w; a1.w += xv.w*w;
        }
        a0.x += a1.x; a0.y += a1.y; a0.z += a1.z; a0.w += a1.w;
        part_sh[r][c] = a0;
    }
    __syncthreads();                     // B5

    // ---- summaryB ----
    if (t < C4) {
        float d0 = 0.f, d1 = 0.f, d2 = 0.f, d3 = 0.f;
        #pragma unroll
        for (int i = 0; i < 32; ++i) {
            d0 += w_sh[1][i];      d1 += w_sh[1][32 + i];
            d2 += w_sh[1][64 + i]; d3 += w_sh[1][96 + i];
        }
        const float inv = 1.0f / fmaxf((d0 + d1) + (d2 + d3), 1e-6f);
        float4 s = part_sh[0][t];
        #pragma unroll
        for (int g = 1; g < NR; ++g) {
            const float4 p = part_sh[g][t];
            s.x += p.x; s.y += p.y; s.z += p.z; s.w += p.w;
        }
        s.x *= inv; s.y *= inv; s.z *= inv; s.w *= inv;
        ((float4*)summ)[t] = s;
    }
    __syncthreads();                     // B6

    // ---- matvecB ----
    {
        float4 a = make_float4(0.f, 0.f, 0.f, 0.f);
        const float4* __restrict__ wv4 = (const float4*)Wv;
        const int e0 = r * (DM / NR);
        #pragma unroll 8
        for (int i = 0; i < DM / NR; ++i) {
            const int   e = e0 + i;
            const float s = summ[e];
            const float4 w = wv4[(size_t)e * C4 + c];
            a.x += s*w.x; a.y += s*w.y; a.z += s*w.z; a.w += s*w.w;
        }
        part_sh[r][c] = a;
    }
    __syncthreads();                     // B7

    // ---- v-finalizeB + storeB (staged rounds from LDS, rest L3-hot) ----
    {
        float4 v = ((const float4*)bv)[c];
        #pragma unroll
        for (int g = 0; g < NR; ++g) {
            const float4 q = part_sh[g][c];
            v.x += q.x; v.y += q.y; v.z += q.z; v.w += q.w;
        }
        float4* __restrict__ oB = (float4*)out + (size_t)bnB * TT * C4;
        #pragma unroll
        for (int i = 0; i < NSTG; ++i) {
            float4 y = stageB[i * 768 + t];
            y.x += v.x; y.y += v.y; y.z += v.z; y.w += v.w;
            nt_store4(&oB[i * 768 + t], y);
        }
        #pragma unroll
        for (int i = 0; i < NREG; ++i) {
            float4 y = pB[(NSTG + i) * 768 + t];
            y.x += v.x; y.y += v.y; y.z += v.z; y.w += v.w;
            nt_store4(&oB[(NSTG + i) * 768 + t], y);
        }
    }
}

extern "C" void kernel_launch(void* const* d_in, const int* in_sizes, int n_in,
                              void* d_out, int out_size, void* d_ws, size_t ws_size,
                              hipStream_t stream) {
    const float* padded = (const float*)d_in[0];
    // d_in[1] sum_token, d_in[2] positions_3d, d_in[3..6] Wq/bq/Wk/bk: dead
    const float* Wv     = (const float*)d_in[7];
    const float* bv     = (const float*)d_in[8];
    const int*   masks  = (const int*)d_in[9];
    float* out = (float*)d_out;

    fused_persist<<<NBLK, 768, 0, stream>>>(padded, masks, Wv, bv, out);
}